// Round 3
// baseline (457.245 us; speedup 1.0000x reference)
//
#include <hip/hip_runtime.h>
#include <math.h>

#define TT 2048   // tokens
#define HH 1024   // hidden
#define EE 8      // experts
#define II 2048   // intermediate
#define N1 4096   // 2*II
#define ALPHA 1.702f
#define LIMIT 7.0f
#define MAXSCHED 40

typedef __attribute__((ext_vector_type(8))) short short8;
typedef __attribute__((ext_vector_type(4))) float floatx4;

#define GLL(g, l) __builtin_amdgcn_global_load_lds(                          \
    (const __attribute__((address_space(1))) void*)(g),                      \
    (__attribute__((address_space(3))) void*)(l), 16, 0, 0)

__device__ __forceinline__ short f2bf(float f) {
  union { float f; unsigned u; } v; v.f = f;
  unsigned r = (v.u + 0x7fffu + ((v.u >> 16) & 1u)) >> 16;
  return (short)r;
}
__device__ __forceinline__ float bf2f(unsigned short s) {
  union { unsigned u; float f; } v; v.u = ((unsigned)s) << 16;
  return v.f;
}

// ---------------- x f32 -> bf16 ----------------
__global__ __launch_bounds__(256) void convert_x(const float* __restrict__ x,
                                                 unsigned short* __restrict__ xb) {
  const size_t off = ((size_t)blockIdx.x * blockDim.x + threadIdx.x) * 8;
  const float4 v0 = *(const float4*)(x + off);
  const float4 v1 = *(const float4*)(x + off + 4);
  short8 s;
  s[0]=f2bf(v0.x); s[1]=f2bf(v0.y); s[2]=f2bf(v0.z); s[3]=f2bf(v0.w);
  s[4]=f2bf(v1.x); s[5]=f2bf(v1.y); s[6]=f2bf(v1.z); s[7]=f2bf(v1.w);
  *(short8*)(xb + off) = s;
}

// ---------------- router: logits -> softmax -> top2 ----------------
__global__ __launch_bounds__(256) void router_kernel(
    const float* __restrict__ x, const float* __restrict__ rw,
    const float* __restrict__ rb, int* __restrict__ topk_idx,
    float* __restrict__ topk_w) {
  const int t = blockIdx.x;
  const float* xr = x + (size_t)t * HH;
  const int lane = threadIdx.x & 63;
  const int wave = threadIdx.x >> 6;
  float xv[16];
#pragma unroll
  for (int i = 0; i < 16; i++) xv[i] = xr[lane + i * 64];
  __shared__ float logits[EE];
#pragma unroll
  for (int ee = 0; ee < 2; ee++) {
    const int e = wave * 2 + ee;
    const float* wr = rw + (size_t)e * HH;
    float s = 0.f;
#pragma unroll
    for (int i = 0; i < 16; i++) s += xv[i] * wr[lane + i * 64];
#pragma unroll
    for (int off = 32; off > 0; off >>= 1) s += __shfl_down(s, off, 64);
    if (lane == 0) logits[e] = s + rb[e];
  }
  __syncthreads();
  if (threadIdx.x == 0) {
    float sc[EE];
    float mx = -3.4e38f;
    for (int i = 0; i < EE; i++) mx = fmaxf(mx, logits[i]);
    float sum = 0.f;
    for (int i = 0; i < EE; i++) { sc[i] = expf(logits[i] - mx); sum += sc[i]; }
    const float inv = 1.f / sum;
    int i0 = 0;
    for (int i = 1; i < EE; i++) if (sc[i] > sc[i0]) i0 = i;
    int i1 = (i0 == 0) ? 1 : 0;
    for (int i = 0; i < EE; i++) if (i != i0 && sc[i] > sc[i1]) i1 = i;
    topk_idx[t * 2 + 0] = i0;
    topk_idx[t * 2 + 1] = i1;
    topk_w[t * 2 + 0] = sc[i0] * inv;
    topk_w[t * 2 + 1] = sc[i1] * inv;
  }
}

// ---------------- token->expert compaction + schedule ----------------
__global__ void assign_kernel(const int* __restrict__ topk_idx,
                              int* __restrict__ counts, int* __restrict__ rows) {
  const int id = blockIdx.x * blockDim.x + threadIdx.x;
  if (id >= TT * 2) return;
  const int e = topk_idx[id];
  const int slot = atomicAdd(&counts[e], 1);
  rows[e * TT + slot] = id;  // entry = t*2 + k
}

__global__ void sched_kernel(const int* __restrict__ counts,
                             int* __restrict__ sched, int* __restrict__ nsched) {
  if (threadIdx.x == 0) {
    int n = 0;
    for (int e = 0; e < EE; e++) {
      const int mt = (counts[e] + 127) >> 7;
      for (int m = 0; m < mt; m++) sched[n++] = (e << 8) | m;
    }
    nsched[0] = n;
  }
}

// ============ GEMM1: A (x_bf gathered, LDS chunks) x B (gup f32 direct) ============
__global__ __launch_bounds__(256, 3) void gemm_gu(
    const unsigned short* __restrict__ x_bf,
    const float* __restrict__ gup,
    const float* __restrict__ gub,
    const int* __restrict__ counts, const int* __restrict__ rows,
    const int* __restrict__ sched, const int* __restrict__ nsched,
    unsigned short* __restrict__ gu) {
  const int sid = blockIdx.y;
  if (sid >= nsched[0]) return;
  const int sv = sched[sid];
  const int e = sv >> 8, mtile = sv & 255;
  const int count = counts[e] - mtile * 128;
  const int ntile = blockIdx.x;
  const int* rl = rows + e * TT + mtile * 128;

  __shared__ short As[128 * 128];  // [m][k-chunk 128], 16B-slot = koct ^ (m&15)

  const int tid = threadIdx.x;
  const int lane = tid & 63, wave = tid >> 6;
  const int quad = lane >> 4, r16 = lane & 15;
  const int wm = (wave & 1) << 6, wn = (wave >> 1) << 6;

  // A staging sources: wave stages rows [wave*32, wave*32+32), 8 GLL/chunk
  const unsigned short* asrc[8];
#pragma unroll
  for (int p = 0; p < 8; p++) {
    const int m = wave * 32 + p * 4 + (lane >> 4);
    const int cm = (m < count) ? m : 0;
    const int g = (lane & 15) ^ (m & 15);
    asrc[p] = x_bf + (size_t)(rl[cm] >> 1) * HH + g * 8;
  }

  // B: per-lane direct f32 loads from [k][n] layout
  const int nbase = ntile * 128 + wn + r16;
  int voff[8];
#pragma unroll
  for (int j = 0; j < 8; j++) voff[j] = (quad * 8 + j) * N1 + nbase;
  const float* bbase = gup + (size_t)e * HH * N1;

  floatx4 acc[4][4] = {};

  for (int c = 0; c < 8; c++) {   // 8 chunks of 128 k
    __syncthreads();
#pragma unroll
    for (int p = 0; p < 8; p++)
      GLL(asrc[p] + c * 128, &As[(wave * 32 + p * 4) * 128]);
    __syncthreads();
#pragma unroll 2
    for (int kt = 0; kt < 4; kt++) {
      short8 af[4];
#pragma unroll
      for (int i = 0; i < 4; i++) {
        const int m = wm + i * 16 + r16;
        const int sl = (kt * 4 + quad) ^ r16;
        af[i] = *(const short8*)&As[m * 128 + sl * 8];
      }
#pragma unroll
      for (int f = 0; f < 4; f++) {
        float bv[8];
#pragma unroll
        for (int j = 0; j < 8; j++) bv[j] = bbase[voff[j] + f * 16];
        union { unsigned u[4]; short8 s8; } bp;
#pragma unroll
        for (int j = 0; j < 4; j++)
          bp.u[j] = __builtin_amdgcn_perm(__float_as_uint(bv[2 * j + 1]),
                                          __float_as_uint(bv[2 * j]), 0x07060302u);
#pragma unroll
        for (int i = 0; i < 4; i++)
          acc[i][f] = __builtin_amdgcn_mfma_f32_16x16x32_bf16(af[i], bp.s8, acc[i][f], 0, 0, 0);
      }
#pragma unroll
      for (int j = 0; j < 8; j++) voff[j] += 32 * N1;
    }
  }

  const float* bias = gub + (size_t)e * N1 + ntile * 128;
#pragma unroll
  for (int i = 0; i < 4; i++) {
#pragma unroll
    for (int reg = 0; reg < 4; reg++) {
      const int rrow = wm + i * 16 + quad * 4 + reg;
      if (rrow < count) {
        const int ent = rl[rrow];
        unsigned short* orow = gu + (size_t)ent * N1 + ntile * 128;
#pragma unroll
        for (int f = 0; f < 4; f++) {
          const int cc = wn + f * 16 + r16;
          orow[cc] = (unsigned short)f2bf(acc[i][f][reg] + bias[cc]);
        }
      }
    }
  }
}

// ---------------- activation: gu -> act (bf16) ----------------
__global__ __launch_bounds__(256) void act_kernel(const unsigned short* __restrict__ gu,
                                                  unsigned short* __restrict__ act) {
  const int id = blockIdx.x * blockDim.x + threadIdx.x;
  const int r = id >> 8;
  const int i8 = (id & 255) * 8;
  const short8 g8 = *(const short8*)(gu + (size_t)r * N1 + i8);
  const short8 u8 = *(const short8*)(gu + (size_t)r * N1 + II + i8);
  short8 o;
#pragma unroll
  for (int j = 0; j < 8; j++) {
    float g = bf2f((unsigned short)g8[j]);
    float u = bf2f((unsigned short)u8[j]);
    g = fminf(g, LIMIT);
    u = fminf(fmaxf(u, -LIMIT), LIMIT);
    const float glu = g / (1.f + expf(-g * ALPHA));
    o[j] = f2bf((u + 1.f) * glu);
  }
  *(short8*)(act + (size_t)r * II + i8) = o;
}

// ============ GEMM2: A (act, LDS chunks) x B (dp f32 direct), splitk=4 ============
__global__ __launch_bounds__(256, 3) void gemm_down(
    const unsigned short* __restrict__ act,
    const float* __restrict__ dp,
    const int* __restrict__ counts, const int* __restrict__ rows,
    const int* __restrict__ sched, const int* __restrict__ nsched,
    float* __restrict__ dout) {
  const int sid = blockIdx.y;
  if (sid >= nsched[0]) return;
  const int sv = sched[sid];
  const int e = sv >> 8, mtile = sv & 255;
  const int count = counts[e] - mtile * 128;
  const int ntile = blockIdx.x;
  const int kbase = blockIdx.z * (II / 4);
  const int* rl = rows + e * TT + mtile * 128;

  __shared__ short As[128 * 128];

  const int tid = threadIdx.x;
  const int lane = tid & 63, wave = tid >> 6;
  const int quad = lane >> 4, r16 = lane & 15;
  const int wm = (wave & 1) << 6, wn = (wave >> 1) << 6;

  const unsigned short* asrc[8];
#pragma unroll
  for (int p = 0; p < 8; p++) {
    const int m = wave * 32 + p * 4 + (lane >> 4);
    const int cm = (m < count) ? m : 0;
    const int g = (lane & 15) ^ (m & 15);
    asrc[p] = act + (size_t)rl[cm] * II + kbase + g * 8;
  }

  const int nbase = ntile * 128 + wn + r16;
  int voff[8];
#pragma unroll
  for (int j = 0; j < 8; j++) voff[j] = (kbase + quad * 8 + j) * HH + nbase;
  const float* bbase = dp + (size_t)e * II * HH;

  floatx4 acc[4][4] = {};

  for (int c = 0; c < 4; c++) {   // 4 chunks of 128 k (512 k per split)
    __syncthreads();
#pragma unroll
    for (int p = 0; p < 8; p++)
      GLL(asrc[p] + c * 128, &As[(wave * 32 + p * 4) * 128]);
    __syncthreads();
#pragma unroll 2
    for (int kt = 0; kt < 4; kt++) {
      short8 af[4];
#pragma unroll
      for (int i = 0; i < 4; i++) {
        const int m = wm + i * 16 + r16;
        const int sl = (kt * 4 + quad) ^ r16;
        af[i] = *(const short8*)&As[m * 128 + sl * 8];
      }
#pragma unroll
      for (int f = 0; f < 4; f++) {
        float bv[8];
#pragma unroll
        for (int j = 0; j < 8; j++) bv[j] = bbase[voff[j] + f * 16];
        union { unsigned u[4]; short8 s8; } bp;
#pragma unroll
        for (int j = 0; j < 4; j++)
          bp.u[j] = __builtin_amdgcn_perm(__float_as_uint(bv[2 * j + 1]),
                                          __float_as_uint(bv[2 * j]), 0x07060302u);
#pragma unroll
        for (int i = 0; i < 4; i++)
          acc[i][f] = __builtin_amdgcn_mfma_f32_16x16x32_bf16(af[i], bp.s8, acc[i][f], 0, 0, 0);
      }
#pragma unroll
      for (int j = 0; j < 8; j++) voff[j] += 32 * HH;
    }
  }

#pragma unroll
  for (int i = 0; i < 4; i++) {
#pragma unroll
    for (int reg = 0; reg < 4; reg++) {
      const int rrow = wm + i * 16 + quad * 4 + reg;
      if (rrow < count) {
        const int ent = rl[rrow];
        float* orow = dout + (size_t)ent * HH + ntile * 128;
#pragma unroll
        for (int f = 0; f < 4; f++) {
          const int cc = wn + f * 16 + r16;
          atomicAdd(&orow[cc], acc[i][f][reg]);
        }
      }
    }
  }
}

// ---------------- combine ----------------
__global__ __launch_bounds__(256) void combine_kernel(
    const float* __restrict__ dout, const float* __restrict__ tw,
    const int* __restrict__ tidx, const float* __restrict__ db,
    float* __restrict__ out) {
  const int id = blockIdx.x * blockDim.x + threadIdx.x;
  const int t = id >> 8;
  const int h = (id & 255) * 4;
  const float w0 = tw[t * 2], w1 = tw[t * 2 + 1];
  const int e0 = tidx[t * 2], e1 = tidx[t * 2 + 1];
  const float4 a = *(const float4*)(dout + (size_t)(2 * t) * HH + h);
  const float4 b = *(const float4*)(dout + (size_t)(2 * t + 1) * HH + h);
  const float4 b0 = *(const float4*)(db + (size_t)e0 * HH + h);
  const float4 b1 = *(const float4*)(db + (size_t)e1 * HH + h);
  float4 o;
  o.x = w0 * (a.x + b0.x) + w1 * (b.x + b1.x);
  o.y = w0 * (a.y + b0.y) + w1 * (b.y + b1.y);
  o.z = w0 * (a.z + b0.z) + w1 * (b.z + b1.z);
  o.w = w0 * (a.w + b0.w) + w1 * (b.w + b1.w);
  *(float4*)(out + (size_t)t * HH + h) = o;
}

extern "C" void kernel_launch(void* const* d_in, const int* in_sizes, int n_in,
                              void* d_out, int out_size, void* d_ws, size_t ws_size,
                              hipStream_t stream) {
  const float* x   = (const float*)d_in[0];
  const float* rw  = (const float*)d_in[1];
  const float* rb  = (const float*)d_in[2];
  const float* gup = (const float*)d_in[3];
  const float* gub = (const float*)d_in[4];
  const float* dp  = (const float*)d_in[5];
  const float* db  = (const float*)d_in[6];
  float* out = (float*)d_out;

  char* ws = (char*)d_ws;
  int*   topk_idx = (int*)(ws + 0);            // 16 KB
  float* topk_w   = (float*)(ws + 16384);      // 16 KB
  int*   counts   = (int*)(ws + 32768);        // 256 B
  int*   nsched   = (int*)(ws + 33024);        // 256 B
  int*   sched    = (int*)(ws + 33280);        // 256 B
  int*   rows     = (int*)(ws + 36864);        // 64 KB
  unsigned short* x_bf = (unsigned short*)(ws + (1u << 20));   // 4 MB
  unsigned short* gu   = (unsigned short*)(ws + 8388608);      // 33.5 MB
  unsigned short* act  = (unsigned short*)(ws + 50331648);     // 16.8 MB
  float*          dout = (float*)(ws + 75497472);              // 16.8 MB
  // total < 96 MB

  convert_x<<<TT * HH / (256 * 8), 256, 0, stream>>>(x, x_bf);
  router_kernel<<<TT, 256, 0, stream>>>(x, rw, rb, topk_idx, topk_w);
  hipMemsetAsync(counts, 0, 64, stream);
  assign_kernel<<<(TT * 2 + 255) / 256, 256, 0, stream>>>(topk_idx, counts, rows);
  sched_kernel<<<1, 64, 0, stream>>>(counts, sched, nsched);
  gemm_gu<<<dim3(N1 / 128, MAXSCHED), 256, 0, stream>>>(
      x_bf, gup, gub, counts, rows, sched, nsched, gu);
  act_kernel<<<TT * 2 * II / (256 * 8), 256, 0, stream>>>(gu, act);
  hipMemsetAsync(dout, 0, (size_t)TT * 2 * HH * 4, stream);
  gemm_down<<<dim3(HH / 128, MAXSCHED, 4), 256, 0, stream>>>(
      act, dp, counts, rows, sched, nsched, dout);
  combine_kernel<<<(TT * HH / 4) / 256, 256, 0, stream>>>(dout, topk_w, topk_idx, db, out);
}